// Round 7
// baseline (88.793 us; speedup 1.0000x reference)
//
#include <hip/hip_runtime.h>
#include <hip/hip_bf16.h>

#define NN 4096
#define DD 768
#define CCL 97
#define KS 48                // DD/16 k-steps (K=16 per 32x32x16 MFMA)
#define NTW 2080             // 64*65/2 upper-triangle 64x64 tiles (one per wave)
#define NBLK 520             // NTW/4 waves per 256-thread block
#define FSCALE 16.0f         // fp8 pre-scale; sims = acc / (FSCALE^2 * TAU)

typedef __attribute__((ext_vector_type(2))) long i64x2;
typedef __attribute__((ext_vector_type(16))) float f32x16;

// workspace layout (bytes)
#define SZ_FT    (NN*DD)                    // 3.1 MB fp8 fragment-tiled F (L2-resident)
#define OFF_ROWP (SZ_FT)                    // row_part[2080][6][32] f32 = 1.60 MB
#define OFF_COLP (OFF_ROWP + NTW*192*4)     // col_part[2080][64][3] f32 = 1.60 MB
#define OFF_BITS (OFF_COLP + NTW*64*12)     // 4096 * 16B
#define OFF_LM   (OFF_BITS + NN*16)         // 4096 f32
#define OFF_PART (OFF_LM + NN*4)            // 64 blocks x 3 f32 loss partials

__device__ __forceinline__ ulonglong2 shfl_bits(ulonglong2 v, int src) {
  ulonglong2 r;
  r.x = __shfl((unsigned long long)v.x, src, 64);
  r.y = __shfl((unsigned long long)v.y, src, 64);
  return r;
}

__device__ __forceinline__ bool ovl(ulonglong2 a, ulonglong2 b) {
  return ((a.x & b.x) | (a.y & b.y)) != 0ULL;
}

// one wave per row: pack 97 labels into 2x u64 via ballot; label_mask
__global__ void prep_bits_kernel(const int* __restrict__ labels,
                                 ulonglong2* __restrict__ bits,
                                 float* __restrict__ lm) {
  int gw = (blockIdx.x * blockDim.x + threadIdx.x) >> 6;
  int lane = threadIdx.x & 63;
  if (gw >= NN) return;
  const int* lr = labels + (long)gw * CCL;
  int v0 = lr[lane];
  int c1 = 64 + lane;
  int v1 = (c1 < CCL) ? lr[c1] : 0;
  unsigned long long m0 = __ballot(v0 == 1);
  unsigned long long m1 = __ballot(v1 == 1);
  if (lane == 0) {
    bits[gw] = make_ulonglong2(m0, m1);
    lm[gw] = (lr[0] != 1) ? 1.0f : 0.0f;
  }
}

// f32 [N][D] -> fp8 e4m3 (x FSCALE), packed per 64-row panel in MFMA order:
// chunk(g64, ks) = 1KB at (g64*KS+ks)*1024; lane l's 16B slot holds
//   bytes 0-7  : row g64*64 + (l&31)      (rows 0..31 fragment)
//   bytes 8-15 : row g64*64 + 32 + (l&31) (rows 32..63 fragment)
// with k = ks*16 + (l>>5)*8 .. +7 in each 8B group
__global__ void convert_kernel(const float* __restrict__ F, char* __restrict__ Ft) {
  int idx = blockIdx.x * 256 + threadIdx.x;      // 0 .. NN*96-1 (8 f32 per thread)
  int r = idx / 96, kc = idx - r * 96;
  const float* src = F + (long)r * DD + kc * 8;
  float f[8];
#pragma unroll
  for (int j = 0; j < 8; ++j) f[j] = src[j] * FSCALE;
  int lo = __builtin_amdgcn_cvt_pk_fp8_f32(f[0], f[1], 0, false);
  lo = __builtin_amdgcn_cvt_pk_fp8_f32(f[2], f[3], lo, true);
  int hi = __builtin_amdgcn_cvt_pk_fp8_f32(f[4], f[5], 0, false);
  hi = __builtin_amdgcn_cvt_pk_fp8_f32(f[6], f[7], hi, true);
  int g = r >> 6, ks = kc >> 1, hf = kc & 1;
  long off = (long)(g * KS + ks) * 1024 + (hf * 32 + (r & 31)) * 16 + ((r >> 5) & 1) * 8;
  *((int2*)(Ft + off)) = make_int2(lo, hi);
}

// one independent 64x64 tile per wave; fp8 operands; no LDS/barriers/atomics
__global__ __launch_bounds__(256) void main_kernel(
    const char* __restrict__ Ft, const ulonglong2* __restrict__ bits,
    float* __restrict__ row_part, float* __restrict__ col_part) {
  const int lane = threadIdx.x & 63;
  const int wave = threadIdx.x >> 6;

  // XCD swizzle on blocks (520 = 8*65, bijective); 4 consecutive tiles per block
  int b0 = blockIdx.x;
  int blk = (b0 & 7) * 65 + (b0 >> 3);
  int t = blk * 4 + wave;                 // 0..2079
  // triangular decode over 64 row-groups (i <= j)
  int i = (int)((129.0f - sqrtf(16641.0f - 8.0f * (float)t)) * 0.5f);
  if (i > 63) i = 63;
  if (i < 0) i = 0;
  while (64 * (i + 1) - ((i + 1) * i) / 2 <= t) ++i;
  while (64 * i - (i * (i - 1)) / 2 > t) --i;
  const int ti = i;
  const int tj = t - (64 * i - i * (i - 1) / 2) + i;
  const bool offdiag = (ti != tj);
  const int R0 = ti * 64, C0 = tj * 64;

  const char* pa = Ft + (long)(tj * KS) * 1024 + lane * 16;  // col panel (A)
  const char* pb = Ft + (long)(ti * KS) * 1024 + lane * 16;  // row panel (B)

  f32x16 acc00, acc01, acc10, acc11;     // acc[cj][ri]
  acc00 = (f32x16)(0.f); acc01 = (f32x16)(0.f);
  acc10 = (f32x16)(0.f); acc11 = (f32x16)(0.f);

#define LOADS(V, ks) do {                                   \
    V##A = *(const i64x2*)(pa + (ks) * 1024);               \
    V##B = *(const i64x2*)(pb + (ks) * 1024);               \
  } while (0)
#define MM(V) do {                                                                  \
    acc00 = __builtin_amdgcn_mfma_f32_32x32x16_fp8_fp8(V##A.x, V##B.x, acc00, 0, 0, 0); \
    acc01 = __builtin_amdgcn_mfma_f32_32x32x16_fp8_fp8(V##A.x, V##B.y, acc01, 0, 0, 0); \
    acc10 = __builtin_amdgcn_mfma_f32_32x32x16_fp8_fp8(V##A.y, V##B.x, acc10, 0, 0, 0); \
    acc11 = __builtin_amdgcn_mfma_f32_32x32x16_fp8_fp8(V##A.y, V##B.y, acc11, 0, 0, 0); \
  } while (0)

  i64x2 wA, wB, xA, xB, yA, yB, zA, zB;   // ring-4
  LOADS(w, 0); LOADS(x, 1); LOADS(y, 2);
#pragma unroll
  for (int kk = 0; kk < 12; ++kk) {
    const int base = kk * 4;
    LOADS(z, base + 3);
    MM(w);
    if (base + 4 < KS) LOADS(w, base + 4);
    MM(x);
    if (base + 5 < KS) LOADS(x, base + 5);
    MM(y);
    if (base + 6 < KS) LOADS(y, base + 6);
    MM(z);
  }
#undef LOADS
#undef MM

  // ---- epilogue (store partials; NO atomics) ----
  // sims[row][col]: row = R0 + ri*32 + (lane&31)   (B operand)
  //                 col = C0 + cj*32 + crow(reg,h) (A operand),
  //                 crow = (reg&3) + 8*(reg>>2) + 4*h,  h = lane>>5
  const float sscale = 1.0f / (FSCALE * FSCALE * 2.0f);   // /TAU too
  const int l31 = lane & 31, h = lane >> 5;
  const ulonglong2 rb0 = bits[R0 + l31];
  const ulonglong2 rb1 = bits[R0 + 32 + l31];
  const ulonglong2 cb0 = bits[C0 + l31];
  const ulonglong2 cb1 = bits[C0 + 32 + l31];

  float rs0 = 0.f, ss0 = 0.f, cs0 = 0.f;
  float rs1 = 0.f, ss1 = 0.f, cs1 = 0.f;

#pragma unroll
  for (int reg = 0; reg < 16; ++reg) {
    const int crow = (reg & 3) + 8 * (reg >> 2) + 4 * h;
    const ulonglong2 cq0 = shfl_bits(cb0, crow);
    const ulonglong2 cq1 = shfl_bits(cb1, crow);
    const bool dgA = (!offdiag) && (l31 == crow);   // diag hits quadrants cj==ri only

    float v00 = acc00[reg] * sscale, v01 = acc01[reg] * sscale;  // cj0: ri0, ri1
    float v10 = acc10[reg] * sscale, v11 = acc11[reg] * sscale;  // cj1: ri0, ri1
    float e00 = __expf(v00), e01 = __expf(v01);
    float e10 = __expf(v10), e11 = __expf(v11);
    bool o00 = ovl(rb0, cq0), o01 = ovl(rb1, cq0);
    bool o10 = ovl(rb0, cq1), o11 = ovl(rb1, cq1);

    float e00m = dgA ? 0.f : e00;
    float e11m = dgA ? 0.f : e11;
    rs0 += e00m + e10;
    rs1 += e01 + e11m;
    if (o00 && !dgA) { ss0 += v00; cs0 += 1.f; }
    if (o10)         { ss0 += v10; cs0 += 1.f; }
    if (o01)         { ss1 += v01; cs1 += 1.f; }
    if (o11 && !dgA) { ss1 += v11; cs1 += 1.f; }

    if (offdiag) {   // column-role partials (symmetric partner rows C0+..)
      float pe0 = e00 + e01;
      float pv0 = (o00 ? v00 : 0.f) + (o01 ? v01 : 0.f);
      float pn0 = (o00 ? 1.f : 0.f) + (o01 ? 1.f : 0.f);
      float pe1 = e10 + e11;
      float pv1 = (o10 ? v10 : 0.f) + (o11 ? v11 : 0.f);
      float pn1 = (o10 ? 1.f : 0.f) + (o11 ? 1.f : 0.f);
#pragma unroll
      for (int d = 1; d < 32; d <<= 1) {
        pe0 += __shfl_xor(pe0, d, 32); pv0 += __shfl_xor(pv0, d, 32);
        pn0 += __shfl_xor(pn0, d, 32); pe1 += __shfl_xor(pe1, d, 32);
        pv1 += __shfl_xor(pv1, d, 32); pn1 += __shfl_xor(pn1, d, 32);
      }
      if (l31 == 0) {          // lanes 0 (h=0) and 32 (h=1): different cols
        float* cp0 = col_part + ((long)t * 64 + crow) * 3;
        cp0[0] = pe0; cp0[1] = pv0; cp0[2] = pn0;
        float* cp1 = col_part + ((long)t * 64 + 32 + crow) * 3;
        cp1[0] = pe1; cp1[1] = pv1; cp1[2] = pn1;
      }
    }
  }

  // row partials: combine half-waves (same rows, disjoint cols), then store
  rs0 += __shfl_xor(rs0, 32, 64); ss0 += __shfl_xor(ss0, 32, 64);
  cs0 += __shfl_xor(cs0, 32, 64);
  rs1 += __shfl_xor(rs1, 32, 64); ss1 += __shfl_xor(ss1, 32, 64);
  cs1 += __shfl_xor(cs1, 32, 64);
  if (lane < 32) {
    float* rp = row_part + (long)t * 192 + lane;
    rp[0]   = rs0; rp[32]  = ss0; rp[64]  = cs0;
    rp[96]  = rs1; rp[128] = ss1; rp[160] = cs1;
  }
}

// one block (1 wave, 64 threads) per row-group g; thread = row r = g*64+lane
__global__ __launch_bounds__(64) void reduce_kernel(
    const float* __restrict__ row_part, const float* __restrict__ col_part,
    const float* __restrict__ lm, float* __restrict__ part) {
  const int g = blockIdx.x;
  const int lane = threadIdx.x;
  const int r = g * 64 + lane;
  const int half = lane >> 5, l = lane & 31;

  float rs = 0.f, ss = 0.f, cs = 0.f;
  // row-role tiles (g, tj), tj = g..63; t = Tbase(g) + (tj - g)
  int t = g * 64 - (g * (g - 1)) / 2;
  for (int tj = g; tj < 64; ++tj, ++t) {
    const float* rp = row_part + (long)t * 192 + half * 96 + l;
    rs += rp[0]; ss += rp[32]; cs += rp[64];
  }
  // col-role tiles (ti, g), ti = 0..g-1; t = Tbase(ti) + (g - ti)
  t = g;
  for (int ti = 0; ti < g; ++ti) {
    const float* cp = col_part + ((long)t * 64 + lane) * 3;
    rs += cp[0]; ss += cp[1]; cs += cp[2];
    t += 63 - ti;
  }

  // per-row loss terms
  float logR = logf(rs);
  float lp1 = (cs > 0.f) ? (ss - cs * logR) / cs : 0.f;
  // logits_max = sims_ii = 0.5 exactly (normalized rows, row max by C-S)
  float lp2 = (cs == 0.f) ? (0.5f - logR) : 0.f;
  float l0 = lm[r];
  float s1 = lp1 * l0, s2 = lp2, slm = l0;
#pragma unroll
  for (int d = 1; d < 64; d <<= 1) {
    s1 += __shfl_xor(s1, d, 64);
    s2 += __shfl_xor(s2, d, 64);
    slm += __shfl_xor(slm, d, 64);
  }
  if (lane == 0) {
    float* p = part + g * 3;
    p[0] = s1; p[1] = s2; p[2] = slm;
  }
}

__global__ __launch_bounds__(64) void final_kernel(const float* __restrict__ part,
                                                   float* __restrict__ out) {
  int lane = threadIdx.x;
  float s1 = part[lane * 3 + 0], s2 = part[lane * 3 + 1], slm = part[lane * 3 + 2];
#pragma unroll
  for (int d = 1; d < 64; d <<= 1) {
    s1 += __shfl_xor(s1, d, 64);
    s2 += __shfl_xor(s2, d, 64);
    slm += __shfl_xor(slm, d, 64);
  }
  if (lane == 0) {
    const float inv = 1.0f / (float)NN;
    out[0] = -2.0f * (s1 * inv + s2 * slm * inv * inv);
  }
}

extern "C" void kernel_launch(void* const* d_in, const int* in_sizes, int n_in,
                              void* d_out, int out_size, void* d_ws, size_t ws_size,
                              hipStream_t stream) {
  const float* F = (const float*)d_in[0];
  const int* labels = (const int*)d_in[1];
  float* out = (float*)d_out;
  char* ws = (char*)d_ws;

  char* Ft = ws;
  float* row_part = (float*)(ws + OFF_ROWP);
  float* col_part = (float*)(ws + OFF_COLP);
  ulonglong2* bits = (ulonglong2*)(ws + OFF_BITS);
  float* lm = (float*)(ws + OFF_LM);
  float* part = (float*)(ws + OFF_PART);

  prep_bits_kernel<<<NN / 4, 256, 0, stream>>>(labels, bits, lm);
  convert_kernel<<<(NN * 96) / 256, 256, 0, stream>>>(F, Ft);
  main_kernel<<<NBLK, 256, 0, stream>>>(Ft, bits, row_part, col_part);
  reduce_kernel<<<64, 64, 0, stream>>>(row_part, col_part, lm, part);
  final_kernel<<<1, 64, 0, stream>>>(part, out);
}

// Round 8
// 50.720 us; speedup vs baseline: 1.7506x; 1.7506x over previous
//
#include <hip/hip_runtime.h>
#include <hip/hip_bf16.h>

#define NN 4096
#define DD 768
#define CCL 97
#define KI 24                // 24 K-iterations of K=32 (2 MFMAs each)
#define FSCALE 16.0f         // fp8 pre-scale; sims = acc / (FSCALE^2 * TAU)

typedef __attribute__((ext_vector_type(2))) long i64x2;
typedef __attribute__((ext_vector_type(16))) float f32x16;

// workspace layout (bytes)
#define SZ_FT    (NN*DD)                    // 3.1 MB fp8 fragment-tiled F (L2-resident)
#define OFF_R    (SZ_FT)
#define OFF_S    (OFF_R + NN*4)
#define OFF_C    (OFF_S + NN*4)
#define OFF_BITS (OFF_C + NN*4)             // 4096 * 16B
#define OFF_LM   (OFF_BITS + NN*16)         // 4096 f32

__device__ __forceinline__ ulonglong2 shfl_bits(ulonglong2 v, int src) {
  ulonglong2 r;
  r.x = __shfl((unsigned long long)v.x, src, 64);
  r.y = __shfl((unsigned long long)v.y, src, 64);
  return r;
}

__device__ __forceinline__ bool ovl(ulonglong2 a, ulonglong2 b) {
  return ((a.x & b.x) | (a.y & b.y)) != 0ULL;
}

// one wave per row: pack 97 labels into 2x u64 via ballot; label_mask; zero accums
__global__ void prep_bits_kernel(const int* __restrict__ labels,
                                 ulonglong2* __restrict__ bits,
                                 float* __restrict__ lm,
                                 float* __restrict__ R, float* __restrict__ S,
                                 float* __restrict__ Cc) {
  int gw = (blockIdx.x * blockDim.x + threadIdx.x) >> 6;
  int lane = threadIdx.x & 63;
  if (gw >= NN) return;
  const int* lr = labels + (long)gw * CCL;
  int v0 = lr[lane];
  int c1 = 64 + lane;
  int v1 = (c1 < CCL) ? lr[c1] : 0;
  unsigned long long m0 = __ballot(v0 == 1);
  unsigned long long m1 = __ballot(v1 == 1);
  if (lane == 0) {
    bits[gw] = make_ulonglong2(m0, m1);
    lm[gw] = (lr[0] != 1) ? 1.0f : 0.0f;
    R[gw] = 0.f; S[gw] = 0.f; Cc[gw] = 0.f;
  }
}

// f32 [N][D] -> fp8 e4m3 (x FSCALE), tiled per 32-row group for 32x32x16 MFMA:
// chunk(g32, ks32) = 1KB at (g32*24+ks32)*1024
// within chunk: row l31 = r&31 occupies bytes [l31*32, +32):
//   [ +0, +8)  k = ks32*32 + 0..7    (MFMA0, lane-half h=0)
//   [+16,+24)  k = ks32*32 + 8..15   (MFMA0, h=1)
//   [ +8,+16)  k = ks32*32 + 16..23  (MFMA1, h=0)
//   [+24,+32)  k = ks32*32 + 24..31  (MFMA1, h=1)
// so lane (l31,h) does ONE 16B load at l31*32 + h*16 = (A.x -> MFMA0, A.y -> MFMA1)
__global__ void convert_kernel(const float* __restrict__ F, char* __restrict__ Ft) {
  int idx = blockIdx.x * 256 + threadIdx.x;      // 0 .. NN*96-1 (8 f32 per thread)
  int r = idx / 96, kc = idx - r * 96;           // kc = which 8-k group
  const float* src = F + (long)r * DD + kc * 8;
  float f[8];
#pragma unroll
  for (int j = 0; j < 8; ++j) f[j] = src[j] * FSCALE;
  int lo = __builtin_amdgcn_cvt_pk_fp8_f32(f[0], f[1], 0, false);
  lo = __builtin_amdgcn_cvt_pk_fp8_f32(f[2], f[3], lo, true);
  int hi = __builtin_amdgcn_cvt_pk_fp8_f32(f[4], f[5], 0, false);
  hi = __builtin_amdgcn_cvt_pk_fp8_f32(f[6], f[7], hi, true);
  int g32 = r >> 5, l31 = r & 31;
  int ks32 = kc >> 2, k8 = kc & 3;               // k = ks32*32 + k8*8
  int hp = k8 & 1, m = k8 >> 1;
  long off = (long)(g32 * KI + ks32) * 1024 + l31 * 32 + hp * 16 + m * 8;
  *((int2*)(Ft + off)) = make_int2(lo, hi);
}

// one 32x32 tile per wave, FULL 128x128 square of tiles (no triangle):
// row stats only, per-wave independent; max TLP. 4 waves/block = 64x64 supertile.
__global__ __launch_bounds__(256, 6) void main_kernel(
    const char* __restrict__ Ft, const ulonglong2* __restrict__ bits,
    float* __restrict__ R, float* __restrict__ S, float* __restrict__ Cc) {
  const int lane = threadIdx.x & 63;
  const int wave = threadIdx.x >> 6;
  const int wi = wave >> 1, wj = wave & 1;
  const int l31 = lane & 31, h = lane >> 5;

  // XCD swizzle (4096 = 8*512, bijective); supertile (I,J) of 64x64
  int b0 = blockIdx.x;
  int nb = (b0 & 7) * 512 + (b0 >> 3);
  const int I = nb >> 6, J = nb & 63;
  const int gB = I * 2 + wi;            // row panel 32-group (B operand)
  const int gA = J * 2 + wj;            // col panel 32-group (A operand)
  const int R0 = gB * 32, C0 = gA * 32;

  const int laddr = l31 * 32 + h * 16;
  const char* pa = Ft + (long)gA * (KI * 1024) + laddr;
  const char* pb = Ft + (long)gB * (KI * 1024) + laddr;

  f32x16 acc = (f32x16)(0.f);
  i64x2 a0, b0v, a1, b1v;

  a0 = *(const i64x2*)(pa); b0v = *(const i64x2*)(pb);
#pragma unroll
  for (int it = 0; it < KI; it += 2) {
    if (it + 1 < KI) {
      a1 = *(const i64x2*)(pa + (it + 1) * 1024);
      b1v = *(const i64x2*)(pb + (it + 1) * 1024);
    }
    acc = __builtin_amdgcn_mfma_f32_32x32x16_fp8_fp8(a0.x, b0v.x, acc, 0, 0, 0);
    acc = __builtin_amdgcn_mfma_f32_32x32x16_fp8_fp8(a0.y, b0v.y, acc, 0, 0, 0);
    if (it + 2 < KI) {
      a0 = *(const i64x2*)(pa + (it + 2) * 1024);
      b0v = *(const i64x2*)(pb + (it + 2) * 1024);
    }
    acc = __builtin_amdgcn_mfma_f32_32x32x16_fp8_fp8(a1.x, b1v.x, acc, 0, 0, 0);
    acc = __builtin_amdgcn_mfma_f32_32x32x16_fp8_fp8(a1.y, b1v.y, acc, 0, 0, 0);
  }

  // ---- epilogue: row stats only ----
  // sims[row = R0 + l31][col = C0 + crow(reg,h)], crow = (reg&3)+8*(reg>>2)+4*h
  const float sscale = 1.0f / (FSCALE * FSCALE * 2.0f);   // includes /TAU
  const ulonglong2 rb = bits[R0 + l31];
  const ulonglong2 cb = bits[C0 + l31];
  const bool samegrp = (gA == gB);

  float rs = 0.f, ss = 0.f, cs = 0.f;
#pragma unroll
  for (int reg = 0; reg < 16; ++reg) {
    const int crow = (reg & 3) + 8 * (reg >> 2) + 4 * h;
    const ulonglong2 cq = shfl_bits(cb, crow);
    const bool dg = samegrp && (crow == l31);
    float v = acc[reg] * sscale;
    float e = __expf(v);
    bool o = ovl(rb, cq);
    if (!dg) {
      rs += e;
      if (o) { ss += v; cs += 1.f; }
    }
  }
  // combine col-halves (h=0: cols 0-3,8-11,16-19,24-27; h=1: the rest)
  rs += __shfl_xor(rs, 32, 64);
  ss += __shfl_xor(ss, 32, 64);
  cs += __shfl_xor(cs, 32, 64);

  // combine the two wj waves (same rows) in LDS, then one atomic set per row
  __shared__ float red[2][3][32];
  if (wj == 1 && lane < 32) {
    red[wi][0][lane] = rs; red[wi][1][lane] = ss; red[wi][2][lane] = cs;
  }
  __syncthreads();
  if (wj == 0 && lane < 32) {
    rs += red[wi][0][lane]; ss += red[wi][1][lane]; cs += red[wi][2][lane];
    int row = R0 + lane;
    atomicAdd(R + row, rs);
    atomicAdd(S + row, ss);
    atomicAdd(Cc + row, cs);
  }
}

__global__ __launch_bounds__(1024) void finalize_kernel(
    const float* __restrict__ R, const float* __restrict__ S,
    const float* __restrict__ Cc, const float* __restrict__ lm,
    float* __restrict__ out) {
  int tid = threadIdx.x;
  float s1 = 0.f, s2 = 0.f, slm = 0.f;
  for (int i = tid; i < NN; i += 1024) {
    float r = R[i], s = S[i], c = Cc[i], l = lm[i];
    float logR = logf(r);
    float lp1 = (c > 0.f) ? (s - c * logR) / c : 0.f;
    // logits_max = sims_ii = 0.5 exactly (normalized rows, row max by C-S)
    float lp2 = (c == 0.f) ? (0.5f - logR) : 0.f;
    s1 += lp1 * l; s2 += lp2; slm += l;
  }
#pragma unroll
  for (int d = 1; d < 64; d <<= 1) {
    s1 += __shfl_xor(s1, d, 64);
    s2 += __shfl_xor(s2, d, 64);
    slm += __shfl_xor(slm, d, 64);
  }
  __shared__ float w1[16], w2[16], w3[16];
  int w = tid >> 6;
  if ((tid & 63) == 0) { w1[w] = s1; w2[w] = s2; w3[w] = slm; }
  __syncthreads();
  if (tid == 0) {
    float a = 0.f, b = 0.f, c2 = 0.f;
    for (int q = 0; q < 16; ++q) { a += w1[q]; b += w2[q]; c2 += w3[q]; }
    const float inv = 1.0f / (float)NN;
    out[0] = -2.0f * (a * inv + b * c2 * inv * inv);
  }
}

extern "C" void kernel_launch(void* const* d_in, const int* in_sizes, int n_in,
                              void* d_out, int out_size, void* d_ws, size_t ws_size,
                              hipStream_t stream) {
  const float* F = (const float*)d_in[0];
  const int* labels = (const int*)d_in[1];
  float* out = (float*)d_out;
  char* ws = (char*)d_ws;

  char* Ft = ws;
  float* R = (float*)(ws + OFF_R);
  float* S = (float*)(ws + OFF_S);
  float* Cc = (float*)(ws + OFF_C);
  ulonglong2* bits = (ulonglong2*)(ws + OFF_BITS);
  float* lm = (float*)(ws + OFF_LM);

  prep_bits_kernel<<<NN / 4, 256, 0, stream>>>(labels, bits, lm, R, S, Cc);
  convert_kernel<<<(NN * 96) / 256, 256, 0, stream>>>(F, Ft);
  main_kernel<<<4096, 256, 0, stream>>>(Ft, bits, R, S, Cc);
  finalize_kernel<<<1, 1024, 0, stream>>>(R, S, Cc, lm, out);
}